// Round 4
// baseline (289.398 us; speedup 1.0000x reference)
//
#include <hip/hip_runtime.h>
#include <hip/hip_bf16.h>

// Problem constants (all powers of two -> index math is shifts/masks)
#define B_   8
#define N_   16384
#define C_   128
#define OUT_ 256
#define E_   262144

// ws word layout (uint32 offsets). ws_size ~537 MB, we use ~73.5 MB.
//   [0,        16384)    : cnt[row]; memset 0 -> per-row edge count (may exceed 64)
//   [16384,    16448)    : ovf_cnt (word 16384) + pad; memset covers it
//   [16448,    540736)   : overflow (row,col) pairs - correctness path only
//   [540736,   1589312)  : tab: fixed-capacity col table, 64 slots/row (16384*64)
//   [1589312,  1605696)  : Wt bf16 [n][k] transposed weights (256x128)
//   [1605696,  9994304)  : x_bf bf16 copy of x (B*N*C shorts)
//   [9994304,  18382912) : aggr bf16 (max_j x_j - x_i), row-major (b,row,c)
#define CNT_OFF  0u
#define OVFC_OFF 16384u
#define OVF_OFF  16448u
#define TAB_OFF  540736u
#define WT_OFF   1589312u
#define XBF_OFF  1605696u
#define AGGR_OFF 9994304u

typedef __attribute__((ext_vector_type(8))) short bf16x8; // 8 bf16 = 4 VGPRs
typedef __attribute__((ext_vector_type(4))) float f32x4;

__device__ __forceinline__ unsigned short f2bf(float f) { // RNE, no NaN inputs
  unsigned u = __float_as_uint(f);
  u += 0x7FFFu + ((u >> 16) & 1u);
  return (unsigned short)(u >> 16);
}
__device__ __forceinline__ float gelu_exact(float v) {
  return 0.5f * v * (1.0f + erff(v * 0.70710678118654752f));
}
__device__ __forceinline__ unsigned umin_(unsigned a, unsigned b) {
  return a < b ? a : b;
}

// ------------- kernel 1: fused x->bf16 | direct edge-table build | Wt prep ------
// Fixed-capacity table (64 slots/row) built in ONE edge pass with atomic cursors
// (aggr needs the col SET, not order). Overflow rows (P ~ 1e-14 at Poisson(16))
// spill (row,col) pairs to a global list that aggr replays -> correct for ANY
// input. Per-block dtype detect: odd u32 words are int64-highs (==0) or int32
// index values (nonzero w.h.p.); 256 samples/block -> P(wrong) = 16384^-256 ~ 0.
__global__ __launch_bounds__(256) void k_prep(const float* __restrict__ x,
                                              const unsigned* __restrict__ eidx,
                                              const float* __restrict__ W,
                                              unsigned* __restrict__ ws) {
  const unsigned bid = blockIdx.x, tid = threadIdx.x;
  if (bid < 16384u) { // ---- x fp32 -> bf16 packed (4,194,304 float4 slots)
    unsigned i = bid * 256u + tid;
    float4 v = ((const float4*)x)[i];
    uint2 o;
    o.x = (unsigned)f2bf(v.x) | ((unsigned)f2bf(v.y) << 16);
    o.y = (unsigned)f2bf(v.z) | ((unsigned)f2bf(v.w) << 16);
    ((uint2*)(ws + XBF_OFF))[i] = o;
  } else if (bid < 17408u) { // ---- edge-table build, one edge per thread
    __shared__ int flag32;
    if (tid == 0) flag32 = 0;
    __syncthreads();
    unsigned e = (bid - 16384u) * 256u + tid; // 0..262143
    if (eidx[2u * e + 1u] != 0u) flag32 = 1;  // benign race
    __syncthreads();
    int row, col;
    if (flag32) {
      row = (int)eidx[e];
      col = (int)eidx[e + E_];
    } else {
      const long long* p = (const long long*)eidx;
      row = (int)p[e];
      col = (int)p[e + E_];
    }
    unsigned pos = atomicAdd(ws + CNT_OFF + (unsigned)row, 1u);
    if (pos < 64u) {
      ws[TAB_OFF + ((unsigned)row << 6) + pos] = (unsigned)col;
    } else { // correctness-only spill
      unsigned o = atomicAdd(ws + OVFC_OFF, 1u);
      ws[OVF_OFF + 2u * o]      = (unsigned)row;
      ws[OVF_OFF + 2u * o + 1u] = (unsigned)col;
    }
  } else { // ---- W fp32 -> bf16 transposed (128 blocks)
    unsigned t = (bid - 17408u) * 256u + tid; // 0..32767
    unsigned n = t >> 7, k = t & 127u;
    ((unsigned short*)(ws + WT_OFF))[n * 128u + k] = f2bf(W[k * 256u + n]);
  }
}

// ------------ kernel 2: full-row table gather-max, clamped-parallel (bf16) ------
// One wave per (batch,row). 64 lanes = 4 edge-groups x 16 lanes; each lane loads
// uint4 (8 channels) -> one wave-load gathers 4 edges x full 128-ch row (1 KB).
// R3 lesson: with avg deg 16, the serial 8/4/1 tail ladder (3 dependent ~300cy
// L2 round trips) dominated, not the main loop. Max is IDEMPOTENT -> round the
// edge count up and CLAMP the slot index (min(4i+g, d64-1)): re-reading an edge
// is free, so every row becomes a branch-free all-parallel gather:
//   deg<=16 -> 4 independent loads, ONE round trip (57% of rows)
//   deg<=32 -> 8 independent loads, ONE round trip (99.99% of rows)
//   deg> 32 -> clamped 16-chunk loop (rare), then overflow replay if deg>64.
// EXEC HAZARD (R1 bug): every __shfl executes under wave-uniform control flow
// (deg is per-wave-uniform) -> full EXEC, no divergent-source hazard.
// batch = blockIdx&7 -> per-XCD gather slice is the 4 MB x_bf batch slice
// (L2-resident under round-robin dispatch). Max trick: fmax on raw u32 (hi
// channel; garbage low mantissa can't flip a bf16-level compare) and on u<<16
// (lo channel, exact).
__global__ __launch_bounds__(256) void k_aggr(const uint4* __restrict__ xbf4,
                                              const unsigned* __restrict__ ws,
                                              uint4* __restrict__ aggr4) {
  const unsigned bi = blockIdx.x;            // 32768 = 4096 rowgroups x 8 batches
  const unsigned b  = bi & 7u;
  const unsigned rg = bi >> 3;               // 0..4095
  const unsigned row = (rg << 2) | (threadIdx.x >> 6); // wave <-> row
  const unsigned lane = threadIdx.x & 63u;
  const unsigned g  = lane >> 4;             // edge subgroup 0..3
  const unsigned ln = lane & 15u;            // uint4 slot within the row
  const uint4* xb = xbf4 + ((size_t)b << 18); // rows stride 16 uint4

  const unsigned deg = ws[CNT_OFF + row];    // wave-uniform (row is per-wave)
  const bool has = (deg != 0u);
  const unsigned d64 = deg < 64u ? deg : 64u;

  // issue all prologue loads up front: col slots, own row (epilogue operand)
  const unsigned cpre = ws[TAB_OFF + (row << 6) + lane]; // slots>=deg: garbage,
                                                         // provably never used
  const uint4 xw = xb[((size_t)row << 4) + ln];          // hoisted off epilogue

  float mlo[4], mhi[4];
#pragma unroll
  for (int r = 0; r < 4; ++r) { mlo[r] = -INFINITY; mhi[r] = -INFINITY; }

#define MAX1(a, r)                                                          \
  mhi[r] = fmaxf(mhi[r], __uint_as_float(a));                               \
  mlo[r] = fmaxf(mlo[r], __uint_as_float((a) << 16));
#define MAX2(a, c, r)                                                       \
  mhi[r] = fmaxf(mhi[r], fmaxf(__uint_as_float(a), __uint_as_float(c)));    \
  mlo[r] = fmaxf(mlo[r],                                                    \
      fmaxf(__uint_as_float((a) << 16), __uint_as_float((c) << 16)));

  if (has) { // wave-uniform
    const unsigned dm1 = d64 - 1u;
    if (d64 <= 16u) { // ---- 4 clamped loads, fully parallel (P = .57)
      unsigned c0 = (unsigned)__shfl((int)cpre, (int)umin_(g,       dm1));
      unsigned c1 = (unsigned)__shfl((int)cpre, (int)umin_(4u + g,  dm1));
      unsigned c2 = (unsigned)__shfl((int)cpre, (int)umin_(8u + g,  dm1));
      unsigned c3 = (unsigned)__shfl((int)cpre, (int)umin_(12u + g, dm1));
      uint4 u0 = xb[((size_t)c0 << 4) + ln];
      uint4 u1 = xb[((size_t)c1 << 4) + ln];
      uint4 u2 = xb[((size_t)c2 << 4) + ln];
      uint4 u3 = xb[((size_t)c3 << 4) + ln];
      MAX2(u0.x, u1.x, 0) MAX2(u0.y, u1.y, 1)
      MAX2(u0.z, u1.z, 2) MAX2(u0.w, u1.w, 3)
      MAX2(u2.x, u3.x, 0) MAX2(u2.y, u3.y, 1)
      MAX2(u2.z, u3.z, 2) MAX2(u2.w, u3.w, 3)
    } else if (d64 <= 32u) { // ---- 8 clamped loads, fully parallel (P = .9999)
      unsigned c[8];
#pragma unroll
      for (int i = 0; i < 8; ++i)
        c[i] = (unsigned)__shfl((int)cpre, (int)umin_(4u * i + g, dm1));
      uint4 u[8];
#pragma unroll
      for (int i = 0; i < 8; ++i) u[i] = xb[((size_t)c[i] << 4) + ln];
#pragma unroll
      for (int i = 0; i < 8; i += 2) {
        MAX2(u[i].x, u[i + 1].x, 0) MAX2(u[i].y, u[i + 1].y, 1)
        MAX2(u[i].z, u[i + 1].z, 2) MAX2(u[i].w, u[i + 1].w, 3)
      }
    } else { // ---- rare: clamped 16-chunk loop, wave-uniform trip count
      for (unsigned t = 0u; t < d64; t += 16u) {
        unsigned c0 = (unsigned)__shfl((int)cpre, (int)umin_(t + g,       dm1));
        unsigned c1 = (unsigned)__shfl((int)cpre, (int)umin_(t + 4u + g,  dm1));
        unsigned c2 = (unsigned)__shfl((int)cpre, (int)umin_(t + 8u + g,  dm1));
        unsigned c3 = (unsigned)__shfl((int)cpre, (int)umin_(t + 12u + g, dm1));
        uint4 u0 = xb[((size_t)c0 << 4) + ln];
        uint4 u1 = xb[((size_t)c1 << 4) + ln];
        uint4 u2 = xb[((size_t)c2 << 4) + ln];
        uint4 u3 = xb[((size_t)c3 << 4) + ln];
        MAX2(u0.x, u1.x, 0) MAX2(u0.y, u1.y, 1)
        MAX2(u0.z, u1.z, 2) MAX2(u0.w, u1.w, 3)
        MAX2(u2.x, u3.x, 0) MAX2(u2.y, u3.y, 1)
        MAX2(u2.z, u3.z, 2) MAX2(u2.w, u3.w, 3)
      }
    }
  }
  if (deg > 64u) { // overflow replay: correctness-only, shuffle-free
    unsigned no = ws[OVFC_OFF];
    for (unsigned i = 0u; i < no; i += 4u) {
      unsigned k = i + g;
      if (k < no && ws[OVF_OFF + 2u * k] == row) {
        unsigned c = ws[OVF_OFF + 2u * k + 1u];
        uint4 u = xb[((size_t)c << 4) + ln];
        MAX1(u.x, 0) MAX1(u.y, 1) MAX1(u.z, 2) MAX1(u.w, 3)
      }
    }
  }
#undef MAX1
#undef MAX2

  // reduce the 4 edge-groups (lane bits 4,5); full EXEC here (reconverged)
#pragma unroll
  for (int r = 0; r < 4; ++r) {
    mlo[r] = fmaxf(mlo[r], __shfl_xor(mlo[r], 16, 64));
    mhi[r] = fmaxf(mhi[r], __shfl_xor(mhi[r], 16, 64));
  }
#pragma unroll
  for (int r = 0; r < 4; ++r) {
    mlo[r] = fmaxf(mlo[r], __shfl_xor(mlo[r], 32, 64));
    mhi[r] = fmaxf(mhi[r], __shfl_xor(mhi[r], 32, 64));
  }

  if (g == 0u) {
    unsigned xv[4] = {xw.x, xw.y, xw.z, xw.w};
    unsigned ox[4];
#pragma unroll
    for (int r = 0; r < 4; ++r) {
      float vlo = has ? mlo[r] : 0.0f;
      float vhi = has ? __uint_as_float(__float_as_uint(mhi[r]) & 0xFFFF0000u)
                      : 0.0f;
      unsigned lo = f2bf(vlo - __uint_as_float(xv[r] << 16));
      unsigned hi = f2bf(vhi - __uint_as_float(xv[r] & 0xFFFF0000u));
      ox[r] = lo | (hi << 16);
    }
    uint4 o = {ox[0], ox[1], ox[2], ox[3]};
    aggr4[(((size_t)b << 14) + row) * 16u + ln] = o;
  }
}

// ---------------- kernel 3: aggr(bf16) @ Wt(bf16) + b, exact GELU ---------------
// One block per 64-row m-tile; loops BOTH n-halves (re-staging Wt_sm between)
// -> each aggr m-tile is read from HBM once, not twice (A traffic 64->32 MB).
// A-fragments read directly from global (the 4 unrolled kc loads cover full
// 64B lines per row). LDS = one Wt half -> 4 blocks/CU.
__global__ __launch_bounds__(256, 4) void k_gemm(const unsigned short* __restrict__ aggr,
                                                 const unsigned short* __restrict__ Wt,
                                                 const float* __restrict__ bias,
                                                 float* __restrict__ out) {
  __shared__ unsigned short Wt_sm[128 * 136]; // 34816 B; stride 136 (2-way free)
  const int tid = threadIdx.x;
  const int mbase = blockIdx.x * 64;

  const int lane = tid & 63;
  const int wv = tid >> 6;   // wave id: rows [wv*16, wv*16+16)
  const int ln = lane & 15;
  const int q = lane >> 4;   // quad

  // A-operand: A[m = lane&15][k = quad*8 + j] -> 16B contiguous in global.
  // Loaded ONCE, reused for both n-halves.
  const unsigned short* arow = aggr + (size_t)(mbase + wv * 16 + ln) * 128 + q * 8;
  bf16x8 af[4];
#pragma unroll
  for (int kc = 0; kc < 4; ++kc) af[kc] = *(const bf16x8*)(arow + kc * 32);

#pragma unroll
  for (int half = 0; half < 2; ++half) {
    const int nbase = half * 128;
    // stage this n-half of Wt (32 KB)
#pragma unroll
    for (int i = 0; i < 8; ++i) {
      int slot = i * 256 + tid;
      int n = slot >> 4, k8 = slot & 15;
      uint4 u = *(const uint4*)(Wt + (size_t)(nbase + n) * 128 + k8 * 8);
      *(uint4*)&Wt_sm[n * 136 + k8 * 8] = u;
    }
    __syncthreads();

    f32x4 acc[8];
#pragma unroll
    for (int f = 0; f < 8; ++f) acc[f] = (f32x4){0.f, 0.f, 0.f, 0.f};

#pragma unroll
    for (int kc = 0; kc < 4; ++kc) {
#pragma unroll
      for (int f = 0; f < 8; ++f) {
        // B-operand: B[k = quad*8 + j][n = lane&15] contiguous in Wt[n][k]
        bf16x8 bf = *(const bf16x8*)&Wt_sm[(f * 16 + ln) * 136 + kc * 32 + q * 8];
        acc[f] = __builtin_amdgcn_mfma_f32_16x16x32_bf16(af[kc], bf, acc[f], 0, 0, 0);
      }
    }

    // Epilogue: C/D layout col = lane&15, row = quad*4 + reg (m89-verified)
#pragma unroll
    for (int f = 0; f < 8; ++f) {
      int n = nbase + f * 16 + ln;
      float bv = bias[n];
#pragma unroll
      for (int r = 0; r < 4; ++r) {
        int m = mbase + wv * 16 + q * 4 + r;
        out[(size_t)m * 256 + n] = gelu_exact(acc[f][r] + bv);
      }
    }
    __syncthreads(); // protect Wt_sm before next half's overwrite
  }
}

extern "C" void kernel_launch(void* const* d_in, const int* in_sizes, int n_in,
                              void* d_out, int out_size, void* d_ws, size_t ws_size,
                              hipStream_t stream) {
  const float* x      = (const float*)d_in[0];
  const unsigned* eid = (const unsigned*)d_in[1];
  const float* W      = (const float*)d_in[2];
  const float* bia    = (const float*)d_in[3];
  float* out          = (float*)d_out;
  unsigned* ws        = (unsigned*)d_ws;

  unsigned short* Wt   = (unsigned short*)(ws + WT_OFF);
  unsigned short* aggr = (unsigned short*)(ws + AGGR_OFF);

  // zero cnt[16384] + ovf_cnt (+pad)
  hipMemsetAsync(ws + CNT_OFF, 0, 16448 * sizeof(unsigned), stream);
  hipLaunchKernelGGL(k_prep, dim3(17536), dim3(256), 0, stream, x, eid, W, ws);
  hipLaunchKernelGGL(k_aggr, dim3(32768), dim3(256), 0, stream,
                     (const uint4*)(ws + XBF_OFF), ws, (uint4*)(ws + AGGR_OFF));
  hipLaunchKernelGGL(k_gemm, dim3(2048),  dim3(256), 0, stream,
                     aggr, Wt, bia, out);
}

// Round 5
// 284.588 us; speedup vs baseline: 1.0169x; 1.0169x over previous
//
#include <hip/hip_runtime.h>
#include <hip/hip_bf16.h>

// Problem constants (all powers of two -> index math is shifts/masks)
#define B_   8
#define N_   16384
#define C_   128
#define OUT_ 256
#define E_   262144

// ws word layout (uint32 offsets). ws_size ~537 MB, we use ~40 MB.
//   [0,        16384)    : cnt[row]; memset 0 -> per-row edge count (may exceed 64)
//   [16384,    16448)    : ovf_cnt (word 16384) + pad; memset covers it
//   [16448,    540736)   : overflow (row,col) pairs - correctness path only
//   [540736,   1589312)  : tab: fixed-capacity col table, 64 slots/row (16384*64)
//   [1589312,  1605696)  : Wt bf16 [n][k] transposed weights (256x128)
//   [1605696,  9994304)  : x_bf bf16 copy of x (B*N*C shorts)
#define CNT_OFF  0u
#define OVFC_OFF 16384u
#define OVF_OFF  16448u
#define TAB_OFF  540736u
#define WT_OFF   1589312u
#define XBF_OFF  1605696u

typedef __attribute__((ext_vector_type(8))) short bf16x8; // 8 bf16 = 4 VGPRs
typedef __attribute__((ext_vector_type(4))) float f32x4;

__device__ __forceinline__ unsigned short f2bf(float f) { // RNE, no NaN inputs
  unsigned u = __float_as_uint(f);
  u += 0x7FFFu + ((u >> 16) & 1u);
  return (unsigned short)(u >> 16);
}
__device__ __forceinline__ float gelu_exact(float v) {
  return 0.5f * v * (1.0f + erff(v * 0.70710678118654752f));
}
__device__ __forceinline__ unsigned umin_(unsigned a, unsigned b) {
  return a < b ? a : b;
}

// ------------- kernel 1: fused x->bf16 | direct edge-table build | Wt prep ------
// Fixed-capacity table (64 slots/row) built in ONE edge pass with atomic cursors
// (the gather needs the col SET, not order). Overflow rows (P ~ 1e-14 at
// Poisson(16)) spill (row,col) pairs to a global list replayed later -> correct
// for ANY input. Per-block dtype detect: odd u32 words are int64-highs (==0) or
// int32 index values (nonzero w.h.p.); 256 samples/block -> P(wrong) ~ 0.
__global__ __launch_bounds__(256) void k_prep(const float* __restrict__ x,
                                              const unsigned* __restrict__ eidx,
                                              const float* __restrict__ W,
                                              unsigned* __restrict__ ws) {
  const unsigned bid = blockIdx.x, tid = threadIdx.x;
  if (bid < 16384u) { // ---- x fp32 -> bf16 packed (4,194,304 float4 slots)
    unsigned i = bid * 256u + tid;
    float4 v = ((const float4*)x)[i];
    uint2 o;
    o.x = (unsigned)f2bf(v.x) | ((unsigned)f2bf(v.y) << 16);
    o.y = (unsigned)f2bf(v.z) | ((unsigned)f2bf(v.w) << 16);
    ((uint2*)(ws + XBF_OFF))[i] = o;
  } else if (bid < 17408u) { // ---- edge-table build, one edge per thread
    __shared__ int flag32;
    if (tid == 0) flag32 = 0;
    __syncthreads();
    unsigned e = (bid - 16384u) * 256u + tid; // 0..262143
    if (eidx[2u * e + 1u] != 0u) flag32 = 1;  // benign race
    __syncthreads();
    int row, col;
    if (flag32) {
      row = (int)eidx[e];
      col = (int)eidx[e + E_];
    } else {
      const long long* p = (const long long*)eidx;
      row = (int)p[e];
      col = (int)p[e + E_];
    }
    unsigned pos = atomicAdd(ws + CNT_OFF + (unsigned)row, 1u);
    if (pos < 64u) {
      ws[TAB_OFF + ((unsigned)row << 6) + pos] = (unsigned)col;
    } else { // correctness-only spill
      unsigned o = atomicAdd(ws + OVFC_OFF, 1u);
      ws[OVF_OFF + 2u * o]      = (unsigned)row;
      ws[OVF_OFF + 2u * o + 1u] = (unsigned)col;
    }
  } else { // ---- W fp32 -> bf16 transposed (128 blocks)
    unsigned t = (bid - 17408u) * 256u + tid; // 0..32767
    unsigned n = t >> 7, k = t & 127u;
    ((unsigned short*)(ws + WT_OFF))[n * 128u + k] = f2bf(W[k * 256u + n]);
  }
}

// -------- kernel 2: FUSED gather-max -> (LDS transpose) -> MFMA gemm -> GELU ----
// R4 lesson: aggr-write + gemm-A-read was a pure 65 MB round trip; the gemm
// m-tile needs exactly the rows this block gathers (wave wv's 16 rows = its
// MFMA m-rows). Phases per block (256 thr = 4 waves, 64 rows, batch b):
//   1) per wave: gather-max 16 rows (2 rows/iter, 8 clamped 1 KB loads in
//      flight; max is idempotent -> index clamp, no tails), aggr bf16 written
//      to a per-wave LDS transpose strip.
//   2) barrier; read MFMA A-fragments from LDS (regs); barrier.
//   3) per n-half: stage Wt half over the SAME LDS, MFMA, bias+GELU, store out.
// EXEC discipline (R1 bug): every __shfl under wave-uniform control flow.
// Empty rows: cpre falls back to own row index -> clamped gathers always touch
// mapped memory; result discarded via `has` at aggr-compute. Max trick: fmax on
// raw u32 (hi channel; garbage low mantissa can't flip a bf16-level compare)
// and on u<<16 (lo channel, exact). batch = blockIdx&7 -> per-XCD 4 MB slice.
__global__ __launch_bounds__(256, 4) void k_ag(const uint4* __restrict__ xbf4,
                                               const unsigned* __restrict__ ws,
                                               const unsigned short* __restrict__ Wt,
                                               const float* __restrict__ bias,
                                               float* __restrict__ out) {
  __shared__ unsigned short sm[128 * 136]; // 34816 B: trans strips, then Wt half
  const unsigned bi = blockIdx.x;          // 2048 = 256 m-tiles x 8 batches
  const unsigned b  = bi & 7u;
  const unsigned mbase = (bi >> 3) << 6;   // 64-row m-tile
  const unsigned tid = threadIdx.x;
  const unsigned wv = tid >> 6;            // wave id: rows [wv*16, wv*16+16)
  const unsigned lane = tid & 63u;
  const unsigned g  = lane >> 4;           // edge subgroup 0..3
  const unsigned ln = lane & 15u;          // uint4 slot within a 128-ch row
  const uint4* xb = xbf4 + ((size_t)b << 18); // rows stride 16 uint4
  const unsigned wbase = mbase + (wv << 4);

#define MAXU4(U, ml, mh)                                                    \
  mh[0] = fmaxf(mh[0], __uint_as_float((U).x));                             \
  ml[0] = fmaxf(ml[0], __uint_as_float((U).x << 16));                       \
  mh[1] = fmaxf(mh[1], __uint_as_float((U).y));                             \
  ml[1] = fmaxf(ml[1], __uint_as_float((U).y << 16));                       \
  mh[2] = fmaxf(mh[2], __uint_as_float((U).z));                             \
  ml[2] = fmaxf(ml[2], __uint_as_float((U).z << 16));                       \
  mh[3] = fmaxf(mh[3], __uint_as_float((U).w));                             \
  ml[3] = fmaxf(ml[3], __uint_as_float((U).w << 16));

  // ---- phase 1: gather-max, 2 rows per iteration ----
  for (unsigned i = 0u; i < 16u; i += 2u) {
    const unsigned ra = wbase + i, rb = ra + 1u;
    const unsigned dega = ws[CNT_OFF + ra]; // wave-uniform -> scalar
    const unsigned degb = ws[CNT_OFF + rb];
    const unsigned d64a = dega < 64u ? dega : 64u;
    const unsigned d64b = degb < 64u ? degb : 64u;
    const unsigned dm1a = d64a - 1u; // 0xFFFFFFFF when deg==0 (cpre fallback)
    const unsigned dm1b = d64b - 1u;
    const unsigned tva = ws[TAB_OFF + (ra << 6) + lane];
    const unsigned tvb = ws[TAB_OFF + (rb << 6) + lane];
    const unsigned cprea = dega ? tva : ra; // empty row -> gather own row (safe)
    const unsigned cpreb = degb ? tvb : rb;
    const uint4 xwa = xb[((size_t)ra << 4) + ln]; // own-row x (epilogue operand)
    const uint4 xwb = xb[((size_t)rb << 4) + ln];

    float mloa[4], mhia[4], mlob[4], mhib[4];
#pragma unroll
    for (int r = 0; r < 4; ++r) {
      mloa[r] = -INFINITY; mhia[r] = -INFINITY;
      mlob[r] = -INFINITY; mhib[r] = -INFINITY;
    }

    if (dega | degb) { // wave-uniform
      const unsigned mx = d64a > d64b ? d64a : d64b;
      for (unsigned t = 0u; t < mx; t += 16u) { // uniform trips; 8 loads in flight
        unsigned ca[4], cb[4];
#pragma unroll
        for (int k = 0; k < 4; ++k) { // full-EXEC shuffles, clamped source lane
          unsigned e = t + 4u * (unsigned)k + g;
          ca[k] = (unsigned)__shfl((int)cprea, (int)umin_(umin_(e, dm1a), 63u));
          cb[k] = (unsigned)__shfl((int)cpreb, (int)umin_(umin_(e, dm1b), 63u));
        }
        uint4 ua[4], ub[4];
#pragma unroll
        for (int k = 0; k < 4; ++k) ua[k] = xb[((size_t)ca[k] << 4) + ln];
#pragma unroll
        for (int k = 0; k < 4; ++k) ub[k] = xb[((size_t)cb[k] << 4) + ln];
#pragma unroll
        for (int k = 0; k < 4; ++k) { MAXU4(ua[k], mloa, mhia) }
#pragma unroll
        for (int k = 0; k < 4; ++k) { MAXU4(ub[k], mlob, mhib) }
      }
    }
    if ((dega > 64u) | (degb > 64u)) { // overflow replay: shuffle-free
      unsigned no = ws[OVFC_OFF];
      for (unsigned k2 = g; k2 < no; k2 += 4u) {
        unsigned rr = ws[OVF_OFF + 2u * k2];
        if (rr == ra) {
          uint4 u = xb[((size_t)ws[OVF_OFF + 2u * k2 + 1u] << 4) + ln];
          MAXU4(u, mloa, mhia)
        } else if (rr == rb) {
          uint4 u = xb[((size_t)ws[OVF_OFF + 2u * k2 + 1u] << 4) + ln];
          MAXU4(u, mlob, mhib)
        }
      }
    }

    // reduce across the 4 edge-groups (full EXEC, reconverged)
#pragma unroll
    for (int r = 0; r < 4; ++r) {
      mloa[r] = fmaxf(mloa[r], __shfl_xor(mloa[r], 16, 64));
      mhia[r] = fmaxf(mhia[r], __shfl_xor(mhia[r], 16, 64));
      mloa[r] = fmaxf(mloa[r], __shfl_xor(mloa[r], 32, 64));
      mhia[r] = fmaxf(mhia[r], __shfl_xor(mhia[r], 32, 64));
      mlob[r] = fmaxf(mlob[r], __shfl_xor(mlob[r], 16, 64));
      mhib[r] = fmaxf(mhib[r], __shfl_xor(mhib[r], 16, 64));
      mlob[r] = fmaxf(mlob[r], __shfl_xor(mlob[r], 32, 64));
      mhib[r] = fmaxf(mhib[r], __shfl_xor(mhib[r], 32, 64));
    }

    if (g == 0u) { // write both rows' aggr bf16 to this wave's LDS strip
      const bool hasa = (dega != 0u), hasb = (degb != 0u);
      unsigned xva[4] = {xwa.x, xwa.y, xwa.z, xwa.w};
      unsigned xvb[4] = {xwb.x, xwb.y, xwb.z, xwb.w};
      unsigned oxa[4], oxb[4];
#pragma unroll
      for (int r = 0; r < 4; ++r) {
        float vloa = hasa ? mloa[r] : 0.0f;
        float vhia = hasa ? __uint_as_float(__float_as_uint(mhia[r]) & 0xFFFF0000u) : 0.0f;
        oxa[r] = (unsigned)f2bf(vloa - __uint_as_float(xva[r] << 16)) |
                 ((unsigned)f2bf(vhia - __uint_as_float(xva[r] & 0xFFFF0000u)) << 16);
        float vlob = hasb ? mlob[r] : 0.0f;
        float vhib = hasb ? __uint_as_float(__float_as_uint(mhib[r]) & 0xFFFF0000u) : 0.0f;
        oxb[r] = (unsigned)f2bf(vlob - __uint_as_float(xvb[r] << 16)) |
                 ((unsigned)f2bf(vhib - __uint_as_float(xvb[r] & 0xFFFF0000u)) << 16);
      }
      uint4 oa = {oxa[0], oxa[1], oxa[2], oxa[3]};
      uint4 ob = {oxb[0], oxb[1], oxb[2], oxb[3]};
      *(uint4*)&sm[wv * 2176u + i * 136u + ln * 8u]        = oa;
      *(uint4*)&sm[wv * 2176u + (i + 1u) * 136u + ln * 8u] = ob;
    }
  }
#undef MAXU4

  __syncthreads(); // trans strips complete (also orders vs af reads)

  // ---- phase 2: A-fragments from LDS. lane(ln,q): A[m=ln][ch=kc*32+q*8..+8]
  const unsigned q = g;
  bf16x8 af[4];
#pragma unroll
  for (int kc = 0; kc < 4; ++kc)
    af[kc] = *(const bf16x8*)&sm[wv * 2176u + ln * 136u + (unsigned)kc * 32u + q * 8u];
  __syncthreads(); // af reads drained before Wt overwrites sm

  // ---- phase 3: per n-half: stage Wt, MFMA, bias + exact GELU, store ----
#pragma unroll
  for (int half = 0; half < 2; ++half) {
    const int nbase = half * 128;
#pragma unroll
    for (int i = 0; i < 8; ++i) {
      int slot = i * 256 + (int)tid;
      int n = slot >> 4, k8 = slot & 15;
      uint4 u = *(const uint4*)(Wt + (size_t)(nbase + n) * 128 + k8 * 8);
      *(uint4*)&sm[n * 136 + k8 * 8] = u;
    }
    __syncthreads();

    f32x4 acc[8];
#pragma unroll
    for (int f = 0; f < 8; ++f) acc[f] = (f32x4){0.f, 0.f, 0.f, 0.f};
#pragma unroll
    for (int kc = 0; kc < 4; ++kc) {
#pragma unroll
      for (int f = 0; f < 8; ++f) {
        // B[k=q*8+j][n=f*16+ln] contiguous in Wt[n][k]
        bf16x8 bf = *(const bf16x8*)&sm[(f * 16 + (int)ln) * 136 + kc * 32 + (int)q * 8];
        acc[f] = __builtin_amdgcn_mfma_f32_16x16x32_bf16(af[kc], bf, acc[f], 0, 0, 0);
      }
    }

    // Epilogue: C/D layout col = lane&15, row = quad*4 + reg (m89-verified)
#pragma unroll
    for (int f = 0; f < 8; ++f) {
      int n = nbase + f * 16 + (int)ln;
      float bv = bias[n];
#pragma unroll
      for (int r = 0; r < 4; ++r) {
        unsigned mrow = ((size_t)b << 14) + mbase + (wv << 4) + q * 4u + (unsigned)r;
        out[(size_t)mrow * 256 + n] = gelu_exact(acc[f][r] + bv);
      }
    }
    __syncthreads(); // protect sm before next half's restage
  }
}

extern "C" void kernel_launch(void* const* d_in, const int* in_sizes, int n_in,
                              void* d_out, int out_size, void* d_ws, size_t ws_size,
                              hipStream_t stream) {
  const float* x      = (const float*)d_in[0];
  const unsigned* eid = (const unsigned*)d_in[1];
  const float* W      = (const float*)d_in[2];
  const float* bia    = (const float*)d_in[3];
  float* out          = (float*)d_out;
  unsigned* ws        = (unsigned*)d_ws;

  const unsigned short* Wt = (const unsigned short*)(ws + WT_OFF);

  // zero cnt[16384] + ovf_cnt (+pad)
  hipMemsetAsync(ws + CNT_OFF, 0, 16448 * sizeof(unsigned), stream);
  hipLaunchKernelGGL(k_prep, dim3(17536), dim3(256), 0, stream, x, eid, W, ws);
  hipLaunchKernelGGL(k_ag,   dim3(2048),  dim3(256), 0, stream,
                     (const uint4*)(ws + XBF_OFF), ws, Wt, bia, out);
}